// Round 3
// baseline (93.025 us; speedup 1.0000x reference)
//
#include <hip/hip_runtime.h>

#define TPB 256
#define PER_THREAD 32
#define CHUNK (TPB * PER_THREAD)   // 8192 elements per block

// ---------------------------------------------------------------------------
// Exclusive block-wide scan of one unsigned per thread. wtot is LDS[TPB/64].
// ---------------------------------------------------------------------------
__device__ __forceinline__ unsigned block_excl_scan(unsigned tsum, unsigned* wtot) {
    const int lane = threadIdx.x & 63;
    const int wid  = threadIdx.x >> 6;
    unsigned v = tsum;
#pragma unroll
    for (int off = 1; off < 64; off <<= 1) {
        unsigned u = __shfl_up(v, off, 64);
        if (lane >= off) v += u;
    }
    if (lane == 63) wtot[wid] = v;
    __syncthreads();
    unsigned woff = 0;
    for (int w = 0; w < wid; ++w) woff += wtot[w];
    return woff + v - tsum;   // exclusive prefix for this thread
}

// ---------------------------------------------------------------------------
// Pass 1: per-block positive counts + per-thread 32-bit positivity masks.
// Bit e of thread t's word = positivity of element block*CHUNK + t*32 + e.
// Also resets the ticket counter used by pass 2's fused final reduction.
// ---------------------------------------------------------------------------
__global__ void k_count(const float* __restrict__ score,
                        unsigned* __restrict__ blockCount,
                        unsigned* __restrict__ mask,
                        unsigned* __restrict__ ticket, long n) {
    const long base  = (long)blockIdx.x * CHUNK;
    const int  tid   = threadIdx.x;
    const long tbase = base + (long)tid * PER_THREAD;
    if (blockIdx.x == 0 && tid == 0) *ticket = 0u;   // reset every call
    unsigned m = 0;
    if (tbase + PER_THREAD <= n) {
        const float4* s4 = reinterpret_cast<const float4*>(score + tbase);
#pragma unroll
        for (int q = 0; q < PER_THREAD / 4; ++q) {
            float4 v = s4[q];
            m |= ((unsigned)(v.x > 0.f)) << (4 * q + 0);
            m |= ((unsigned)(v.y > 0.f)) << (4 * q + 1);
            m |= ((unsigned)(v.z > 0.f)) << (4 * q + 2);
            m |= ((unsigned)(v.w > 0.f)) << (4 * q + 3);
        }
    } else {
        for (int e = 0; e < PER_THREAD; ++e) {
            long gi = tbase + e;
            if (gi < n && score[gi] > 0.f) m |= (1u << e);
        }
    }
    if (mask) mask[(size_t)blockIdx.x * TPB + tid] = m;

    unsigned cnt = __popc(m);
#pragma unroll
    for (int off = 32; off > 0; off >>= 1) cnt += __shfl_down(cnt, off, 64);
    __shared__ unsigned wsum[TPB / 64];
    const int lane = tid & 63, wid = tid >> 6;
    if (lane == 0) wsum[wid] = cnt;
    __syncthreads();
    if (tid == 0) {
        unsigned tot = 0;
        for (int w = 0; w < TPB / 64; ++w) tot += wsum[w];
        blockCount[blockIdx.x] = tot;
    }
}

// ---------------------------------------------------------------------------
// Pass 2 (fused): per-block offset/total from blockCount (L2-resident),
// main elementwise+rank computation, block reduce, and last-block-done
// final reduction via device-scope ticket (fixed reduce order => deterministic).
// ---------------------------------------------------------------------------
template <bool USE_MASK>
__global__ void k_main(const float* __restrict__ predict,
                       const float* __restrict__ score,
                       const unsigned* __restrict__ mask,
                       const unsigned* __restrict__ blockCount,
                       double* __restrict__ blockSum,
                       unsigned* __restrict__ ticket,
                       float* __restrict__ out, long n, int B) {
    const int  tid   = threadIdx.x;
    const int  bid   = blockIdx.x;
    const long base  = (long)bid * CHUNK;
    const long tbase = base + (long)tid * PER_THREAD;
    const int  lane  = tid & 63, wid = tid >> 6;

    __shared__ unsigned wtot[TPB / 64];
    __shared__ unsigned wpart[2 * (TPB / 64)];
    __shared__ unsigned s_off, s_P;
    __shared__ double   dsum[TPB / 64];
    __shared__ int      s_last;

    const bool full = (tbase + PER_THREAD <= n);

    // --- this thread's 32-bit positivity mask ---
    unsigned m = 0;
    if (USE_MASK) {
        m = mask[(size_t)bid * TPB + tid];
    } else {
        if (full) {
            const float4* s4 = reinterpret_cast<const float4*>(score + tbase);
#pragma unroll
            for (int q = 0; q < PER_THREAD / 4; ++q) {
                float4 v = s4[q];
                m |= ((unsigned)(v.x > 0.f)) << (4 * q + 0);
                m |= ((unsigned)(v.y > 0.f)) << (4 * q + 1);
                m |= ((unsigned)(v.z > 0.f)) << (4 * q + 2);
                m |= ((unsigned)(v.w > 0.f)) << (4 * q + 3);
            }
        } else {
            for (int e = 0; e < PER_THREAD; ++e) {
                long gi = tbase + e;
                if (gi < n && score[gi] > 0.f) m |= (1u << e);
            }
        }
    }

    unsigned cnt  = __popc(m);
    unsigned excl = block_excl_scan(cnt, wtot);   // within-block exclusive prefix

    // --- per-block exclusive offset + global total from blockCount (L2) ---
    unsigned offp = 0, tot = 0;
    for (int j = tid; j < B; j += TPB) {
        unsigned c = blockCount[j];
        tot  += c;
        offp += (j < bid) ? c : 0u;
    }
#pragma unroll
    for (int off = 32; off > 0; off >>= 1) {
        offp += __shfl_down(offp, off, 64);
        tot  += __shfl_down(tot,  off, 64);
    }
    if (lane == 0) { wpart[2 * wid] = offp; wpart[2 * wid + 1] = tot; }
    __syncthreads();
    if (tid == 0) {
        unsigned o = 0, t = 0;
        for (int w = 0; w < TPB / 64; ++w) { o += wpart[2 * w]; t += wpart[2 * w + 1]; }
        s_off = o; s_P = t;
    }
    __syncthreads();

    const unsigned P = s_P;
    const float    S = (float)P;                        // sum(score): 0/1, exact
    const float invS = 1.0f / S;                        // s value at positives
    const float sumS = (float)((double)invS * (double)P);
    const float rcpSumS = 1.0f / sumS;
    const float Pf = (float)P;
    unsigned run = s_off + excl;   // positives strictly before this thread's 1st elem

    double acc = 0.0;
    if (full) {
        const float4* p4 = reinterpret_cast<const float4*>(predict + tbase);
#pragma unroll
        for (int q = 0; q < PER_THREAD / 4; ++q) {
            float4 pv4 = p4[q];
            float pv[4] = {pv4.x, pv4.y, pv4.z, pv4.w};
#pragma unroll
            for (int j = 0; j < 4; ++j) {
                const int e = 4 * q + j;
                const bool ispos = (m >> e) & 1u;
                const unsigned newrun = run + (ispos ? 1u : 0u);
                const float p = pv[j] * rcpSumS;
                const float kp1  = (float)(newrun + 1u);
                const float posv = p * __builtin_amdgcn_rcpf(kp1)
                                 - invS * __builtin_amdgcn_rcpf(__log2f(kp1));
                const unsigned mr = (unsigned)(tbase + e + 1) - newrun;
                const float negv  = p * __builtin_amdgcn_rcpf(Pf + (float)mr + 1.0f);
                const float t = ispos ? posv : negv;
                acc += (double)(t * t);
                run = newrun;
            }
        }
    } else {
        for (int e = 0; e < PER_THREAD; ++e) {
            long gi = tbase + e;
            if (gi >= n) break;
            const bool ispos = (m >> e) & 1u;
            const unsigned newrun = run + (ispos ? 1u : 0u);
            const float p = predict[gi] * rcpSumS;
            const float kp1  = (float)(newrun + 1u);
            const float posv = p * __builtin_amdgcn_rcpf(kp1)
                             - invS * __builtin_amdgcn_rcpf(__log2f(kp1));
            const unsigned mr = (unsigned)(gi + 1) - newrun;
            const float negv  = p * __builtin_amdgcn_rcpf(Pf + (float)mr + 1.0f);
            const float t = ispos ? posv : negv;
            acc += (double)(t * t);
            run = newrun;
        }
    }

    // --- deterministic block reduce ---
#pragma unroll
    for (int off = 32; off > 0; off >>= 1) acc += __shfl_down(acc, off, 64);
    if (lane == 0) dsum[wid] = acc;
    __syncthreads();
    if (tid == 0) {
        double t = 0.0;
        for (int w = 0; w < TPB / 64; ++w) t += dsum[w];
        blockSum[bid] = t;
        __threadfence();                         // release blockSum (device scope)
        unsigned old = atomicAdd(ticket, 1u);    // device-scope by default
        s_last = (old == (unsigned)B - 1u) ? 1 : 0;
    }
    __syncthreads();

    // --- last-arriving block: final reduce (fixed order => deterministic) ---
    if (s_last) {
        __threadfence();                         // acquire all blockSum writes
        double a2 = 0.0;
        for (int j = tid; j < B; j += TPB)
            a2 += ((volatile double*)blockSum)[j];
#pragma unroll
        for (int off = 32; off > 0; off >>= 1) a2 += __shfl_down(a2, off, 64);
        if (lane == 0) dsum[wid] = a2;
        __syncthreads();
        if (tid == 0) {
            double t = 0.0;
            for (int w = 0; w < TPB / 64; ++w) t += dsum[w];
            out[0] = (float)t;
        }
    }
}

extern "C" void kernel_launch(void* const* d_in, const int* in_sizes, int n_in,
                              void* d_out, int out_size, void* d_ws, size_t ws_size,
                              hipStream_t stream) {
    const float* predict = (const float*)d_in[0];
    const float* score   = (const float*)d_in[1];
    const long n = (long)in_sizes[0];
    const int B = (int)((n + CHUNK - 1) / CHUNK);   // 2048 for N=2^24

    unsigned char* ws = (unsigned char*)d_ws;
    size_t off = 0;
    unsigned* blockCount = (unsigned*)(ws + off); off += (size_t)B * sizeof(unsigned);
    unsigned* ticket     = (unsigned*)(ws + off); off += 64;   // keep alignment
    off = (off + 255) & ~(size_t)255;
    double*   blockSum   = (double*)(ws + off);   off += (size_t)B * sizeof(double);
    off = (off + 255) & ~(size_t)255;
    unsigned* maskBuf    = (unsigned*)(ws + off);
    const size_t maskBytes = (size_t)B * TPB * sizeof(unsigned);
    const bool useMask = (off + maskBytes) <= ws_size;

    k_count<<<B, TPB, 0, stream>>>(score, blockCount, useMask ? maskBuf : nullptr,
                                   ticket, n);
    if (useMask)
        k_main<true><<<B, TPB, 0, stream>>>(predict, nullptr, maskBuf, blockCount,
                                            blockSum, ticket, (float*)d_out, n, B);
    else
        k_main<false><<<B, TPB, 0, stream>>>(predict, score, nullptr, blockCount,
                                             blockSum, ticket, (float*)d_out, n, B);
}

// Round 4
// 41.921 us; speedup vs baseline: 2.2191x; 2.2191x over previous
//
#include <hip/hip_runtime.h>

#define TPB 256
#define PER_THREAD 32
#define CHUNK (TPB * PER_THREAD)   // 8192 elements per block

// ---------------------------------------------------------------------------
// Exclusive block-wide scan of one unsigned per thread. wtot is LDS[TPB/64].
// ---------------------------------------------------------------------------
__device__ __forceinline__ unsigned block_excl_scan(unsigned tsum, unsigned* wtot) {
    const int lane = threadIdx.x & 63;
    const int wid  = threadIdx.x >> 6;
    unsigned v = tsum;
#pragma unroll
    for (int off = 1; off < 64; off <<= 1) {
        unsigned u = __shfl_up(v, off, 64);
        if (lane >= off) v += u;
    }
    if (lane == 63) wtot[wid] = v;
    __syncthreads();
    unsigned woff = 0;
    for (int w = 0; w < wid; ++w) woff += wtot[w];
    return woff + v - tsum;   // exclusive prefix for this thread
}

// ---------------------------------------------------------------------------
// Pass 1: per-block positive counts + per-thread 32-bit positivity masks.
// Bit e of thread t's word = positivity of element block*CHUNK + t*32 + e.
// ---------------------------------------------------------------------------
__global__ void k_count(const float* __restrict__ score,
                        unsigned* __restrict__ blockCount,
                        unsigned* __restrict__ mask, long n) {
    const long base  = (long)blockIdx.x * CHUNK;
    const int  tid   = threadIdx.x;
    const long tbase = base + (long)tid * PER_THREAD;
    unsigned m = 0;
    if (tbase + PER_THREAD <= n) {
        const float4* s4 = reinterpret_cast<const float4*>(score + tbase);
#pragma unroll
        for (int q = 0; q < PER_THREAD / 4; ++q) {
            float4 v = s4[q];
            m |= ((unsigned)(v.x > 0.f)) << (4 * q + 0);
            m |= ((unsigned)(v.y > 0.f)) << (4 * q + 1);
            m |= ((unsigned)(v.z > 0.f)) << (4 * q + 2);
            m |= ((unsigned)(v.w > 0.f)) << (4 * q + 3);
        }
    } else {
        for (int e = 0; e < PER_THREAD; ++e) {
            long gi = tbase + e;
            if (gi < n && score[gi] > 0.f) m |= (1u << e);
        }
    }
    if (mask) mask[(size_t)blockIdx.x * TPB + tid] = m;

    unsigned cnt = __popc(m);
#pragma unroll
    for (int off = 32; off > 0; off >>= 1) cnt += __shfl_down(cnt, off, 64);
    __shared__ unsigned wsum[TPB / 64];
    const int lane = tid & 63, wid = tid >> 6;
    if (lane == 0) wsum[wid] = cnt;
    __syncthreads();
    if (tid == 0) {
        unsigned tot = 0;
        for (int w = 0; w < TPB / 64; ++w) tot += wsum[w];
        blockCount[blockIdx.x] = tot;
    }
}

// ---------------------------------------------------------------------------
// Pass 2: each block derives its own exclusive offset + global total P by
// summing blockCount (written by the PREVIOUS kernel -> plain loads, no
// fences). Then the main elementwise+rank computation -> blockSum[bid].
// NO device-scope fences/atomics anywhere (round-3 lesson: per-block
// agent-scope fences cause an L2 invalidation storm on multi-XCD CDNA4).
// ---------------------------------------------------------------------------
template <bool USE_MASK>
__global__ void k_main(const float* __restrict__ predict,
                       const float* __restrict__ score,
                       const unsigned* __restrict__ mask,
                       const unsigned* __restrict__ blockCount,
                       double* __restrict__ blockSum, long n, int B) {
    const int  tid   = threadIdx.x;
    const int  bid   = blockIdx.x;
    const long base  = (long)bid * CHUNK;
    const long tbase = base + (long)tid * PER_THREAD;
    const int  lane  = tid & 63, wid = tid >> 6;

    __shared__ unsigned wtot[TPB / 64];
    __shared__ unsigned wpart[2 * (TPB / 64)];
    __shared__ unsigned s_off, s_P;
    __shared__ double   dsum[TPB / 64];

    const bool full = (tbase + PER_THREAD <= n);

    // --- this thread's 32-bit positivity mask ---
    unsigned m = 0;
    if (USE_MASK) {
        m = mask[(size_t)bid * TPB + tid];
    } else {
        if (full) {
            const float4* s4 = reinterpret_cast<const float4*>(score + tbase);
#pragma unroll
            for (int q = 0; q < PER_THREAD / 4; ++q) {
                float4 v = s4[q];
                m |= ((unsigned)(v.x > 0.f)) << (4 * q + 0);
                m |= ((unsigned)(v.y > 0.f)) << (4 * q + 1);
                m |= ((unsigned)(v.z > 0.f)) << (4 * q + 2);
                m |= ((unsigned)(v.w > 0.f)) << (4 * q + 3);
            }
        } else {
            for (int e = 0; e < PER_THREAD; ++e) {
                long gi = tbase + e;
                if (gi < n && score[gi] > 0.f) m |= (1u << e);
            }
        }
    }

    unsigned cnt  = __popc(m);
    unsigned excl = block_excl_scan(cnt, wtot);   // within-block exclusive prefix

    // --- per-block exclusive offset + global total from blockCount ---
    unsigned offp = 0, tot = 0;
    for (int j = tid; j < B; j += TPB) {
        unsigned c = blockCount[j];
        tot  += c;
        offp += (j < bid) ? c : 0u;
    }
#pragma unroll
    for (int off = 32; off > 0; off >>= 1) {
        offp += __shfl_down(offp, off, 64);
        tot  += __shfl_down(tot,  off, 64);
    }
    if (lane == 0) { wpart[2 * wid] = offp; wpart[2 * wid + 1] = tot; }
    __syncthreads();
    if (tid == 0) {
        unsigned o = 0, t = 0;
        for (int w = 0; w < TPB / 64; ++w) { o += wpart[2 * w]; t += wpart[2 * w + 1]; }
        s_off = o; s_P = t;
    }
    __syncthreads();

    const unsigned P = s_P;
    const float invS = 1.0f / (float)P;                 // s value at positives
    const float sumS = (float)((double)invS * (double)P);
    const float rcpSumS = 1.0f / sumS;
    const float Pf = (float)P;
    unsigned run = s_off + excl;   // positives strictly before this thread's 1st elem

    double acc = 0.0;
    if (full) {
        const float4* p4 = reinterpret_cast<const float4*>(predict + tbase);
#pragma unroll
        for (int q = 0; q < PER_THREAD / 4; ++q) {
            float4 pv4 = p4[q];
            float pv[4] = {pv4.x, pv4.y, pv4.z, pv4.w};
#pragma unroll
            for (int j = 0; j < 4; ++j) {
                const int e = 4 * q + j;
                const bool ispos = (m >> e) & 1u;
                const unsigned newrun = run + (ispos ? 1u : 0u);
                const float p = pv[j] * rcpSumS;
                const float kp1  = (float)(newrun + 1u);
                const float posv = p * __builtin_amdgcn_rcpf(kp1)
                                 - invS * __builtin_amdgcn_rcpf(__log2f(kp1));
                const unsigned mr = (unsigned)(tbase + e + 1) - newrun;
                const float negv  = p * __builtin_amdgcn_rcpf(Pf + (float)mr + 1.0f);
                const float t = ispos ? posv : negv;
                acc += (double)(t * t);
                run = newrun;
            }
        }
    } else {
        for (int e = 0; e < PER_THREAD; ++e) {
            long gi = tbase + e;
            if (gi >= n) break;
            const bool ispos = (m >> e) & 1u;
            const unsigned newrun = run + (ispos ? 1u : 0u);
            const float p = predict[gi] * rcpSumS;
            const float kp1  = (float)(newrun + 1u);
            const float posv = p * __builtin_amdgcn_rcpf(kp1)
                             - invS * __builtin_amdgcn_rcpf(__log2f(kp1));
            const unsigned mr = (unsigned)(gi + 1) - newrun;
            const float negv  = p * __builtin_amdgcn_rcpf(Pf + (float)mr + 1.0f);
            const float t = ispos ? posv : negv;
            acc += (double)(t * t);
            run = newrun;
        }
    }

    // --- deterministic block reduce ---
#pragma unroll
    for (int off = 32; off > 0; off >>= 1) acc += __shfl_down(acc, off, 64);
    if (lane == 0) dsum[wid] = acc;
    __syncthreads();
    if (tid == 0) {
        double t = 0.0;
        for (int w = 0; w < TPB / 64; ++w) t += dsum[w];
        blockSum[bid] = t;
    }
}

// ---------------------------------------------------------------------------
// Pass 3: deterministic reduce of per-block doubles -> float scalar.
// ---------------------------------------------------------------------------
__global__ void k_final(const double* __restrict__ blockSum,
                        float* __restrict__ out, int B) {
    const int tid = threadIdx.x;
    double acc = 0.0;
    for (int j = tid; j < B; j += TPB) acc += blockSum[j];
#pragma unroll
    for (int off = 32; off > 0; off >>= 1) acc += __shfl_down(acc, off, 64);
    __shared__ double dsum[TPB / 64];
    const int lane = tid & 63, wid = tid >> 6;
    if (lane == 0) dsum[wid] = acc;
    __syncthreads();
    if (tid == 0) {
        double tot = 0.0;
        for (int w = 0; w < TPB / 64; ++w) tot += dsum[w];
        out[0] = (float)tot;
    }
}

extern "C" void kernel_launch(void* const* d_in, const int* in_sizes, int n_in,
                              void* d_out, int out_size, void* d_ws, size_t ws_size,
                              hipStream_t stream) {
    const float* predict = (const float*)d_in[0];
    const float* score   = (const float*)d_in[1];
    const long n = (long)in_sizes[0];
    const int B = (int)((n + CHUNK - 1) / CHUNK);   // 2048 for N=2^24

    unsigned char* ws = (unsigned char*)d_ws;
    size_t off = 0;
    unsigned* blockCount = (unsigned*)(ws + off); off += (size_t)B * sizeof(unsigned);
    off = (off + 255) & ~(size_t)255;
    double*   blockSum   = (double*)(ws + off);   off += (size_t)B * sizeof(double);
    off = (off + 255) & ~(size_t)255;
    unsigned* maskBuf    = (unsigned*)(ws + off);
    const size_t maskBytes = (size_t)B * TPB * sizeof(unsigned);
    const bool useMask = (off + maskBytes) <= ws_size;

    k_count<<<B, TPB, 0, stream>>>(score, blockCount, useMask ? maskBuf : nullptr, n);
    if (useMask)
        k_main<true><<<B, TPB, 0, stream>>>(predict, nullptr, maskBuf, blockCount,
                                            blockSum, n, B);
    else
        k_main<false><<<B, TPB, 0, stream>>>(predict, score, nullptr, blockCount,
                                             blockSum, n, B);
    k_final<<<1, TPB, 0, stream>>>(blockSum, (float*)d_out, B);
}